// Round 7
// baseline (105.469 us; speedup 1.0000x reference)
//
#include <hip/hip_runtime.h>
#include <utility>

#define IMG_H 512
#define IMG_W 512

typedef _Float16 h2 __attribute__((ext_vector_type(2)));

__device__ __forceinline__ h2 h2min(h2 a, h2 b) { return __builtin_elementwise_min(a, b); }
__device__ __forceinline__ h2 h2max(h2 a, h2 b) { return __builtin_elementwise_max(a, b); }

// ---------------------------------------------------------------------------
// Round 15: SCHED_BARRIER PHASE PINNING.
// r6 accounting: 46us = ~1600 VALU instr/thread issued, vs ~550 needed => 3x
// codegen inflation. Scratch ruled out by bandwidth (7.5GB/46us = 163TB/s,
// impossible); LDS=0; 40 arch VGPRs can't hold ~90 live values => the file
// is AGPR-resident (unified-file spill): each CE = 2x accvgpr_read + min/max
// + 2x accvgpr_write = exactly 3x VALU. Root cause hypothesis: pre-RA
// scheduler balloons the flat ~500-op DAG's live ranges far past any budget
// (r2's 8-wide at (256,2): budget 256, arch used 76!), RA spills to AGPR.
// Fix: __builtin_amdgcn_sched_barrier(0) every 16 network ops (+1 after the
// prologue) caps the scheduling window => liveness ~= our regalloc model
// (~90-110) < 128 budget => arch-resident, no shuttle. Prologue VMEM left
// unpinned. Single-variable vs r6.
// Predict: VGPR 40 -> 100-130, kernel 46 -> 18-26us, dur_us 105 -> ~65-75.
// kinds: 0 ce(a,b)  1 mov v[a]=v[b]  2 load v[a]=cols[b]  3 store med[a]=v[b]
//        4 v[a]=min(v[a],v[b])       5 v[b]=max(v[a],v[b])
// ---------------------------------------------------------------------------
struct Op { int kind, a, b; };
constexpr int NSLOT = 352;
constexpr int MAXOPS = 4096;
constexpr int NCOLREG = 56;            // 8 columns x 7 rows, precolored 0..55
struct Prog { Op ops[MAXOPS]; int n; int nphys; bool ok; bool noload; };

constexpr int pow2ceil(int x) { int p = 1; while (p < x) p += p; return p; }

struct Builder {
    Op ops[MAXOPS] = {};
    int n = 0;
    bool pad[NSLOT] = {};
    bool init[NSLOT] = {};
    bool ok = true;

    constexpr void emit(int k, int a, int b) {
        if (n < MAXOPS) ops[n++] = Op{k, a, b}; else ok = false;
    }
    constexpr void load(int s, int c) { emit(2, s, c); pad[s] = false; init[s] = true; }
    constexpr void mov(int d, int s) {
        if (!init[s] || d == s) ok = false;
        emit(1, d, s); pad[d] = pad[s]; init[d] = true;
    }
    constexpr void mkpad(int s) { pad[s] = true; init[s] = true; }
    constexpr void ce_(int a, int b) {
        if (!init[a] || !init[b]) { ok = false; return; }
        if (pad[a] && pad[b]) return;
        if (!pad[a] && pad[b]) return;                      // min stays low: no-op
        if (pad[a] && !pad[b]) {                            // value falls to a
            emit(1, a, b); pad[a] = false; pad[b] = true; return;
        }
        emit(0, a, b);
    }
    constexpr void maxin(int a, int b) {  // v[b] = max(v[a], v[b])
        if (!init[a] || !init[b] || pad[a] || pad[b]) ok = false;
        emit(5, a, b);
    }
    constexpr void minin(int a, int b) {  // v[a] = min(v[a], v[b])
        if (!init[a] || !init[b] || pad[a] || pad[b]) ok = false;
        emit(4, a, b);
    }
    constexpr void sort_run(int base, int len) {
        for (int p = 1; p < len; p += p)
            for (int k = p; k > 0; k /= 2)
                for (int j = k % p; j + k < len; j += k + k)
                    for (int i = 0; i < k; ++i)
                        if (i + j + k < len)
                            if ((i + j) / (p + p) == (i + j + k) / (p + p))
                                ce_(base + i + j, base + i + j + k);
    }
    constexpr void merge_stage(int base, int P) {
        int nn = 2 * P, p = P;
        for (int k = p; k > 0; k /= 2)
            for (int j = k % p; j + k < nn; j += k + k)
                for (int i = 0; i < k; ++i) {
                    int a = i + j, b = i + j + k;
                    if (b < nn && a / (p + p) == b / (p + p)) ce_(base + a, base + b);
                }
    }
    constexpr void load_col(int base, int c) {  // packed col c, sorted
        for (int r = 0; r < 7; ++r) load(base + r, c * 7 + r);
        sort_run(base, 7);
    }
    constexpr void place(int dst, int src, int len, int P) {
        for (int i = 0; i < len; ++i) mov(dst + i, src + i);
        for (int i = len; i < P; ++i) mkpad(dst + i);
    }
    constexpr void merge_to(int dst, int s1, int l1, int s2, int l2) {
        int P = pow2ceil(l1 > l2 ? l1 : l2);
        place(dst, s1, l1, P);
        place(dst + P, s2, l2, P);
        merge_stage(dst, P);
    }
    // rank-24 of sorted-42 at A ∪ sorted-7 at B (min-of-max identity)
    constexpr void select_med49(int T, int A, int B, int o) {
        for (int t = 0; t < 7; ++t) {
            mov(T + t, A + 17 + t);
            maxin(B + 6 - t, T + t);
        }
        mov(T + 7, A + 24);
        minin(T, T + 1); minin(T + 2, T + 3);
        minin(T + 4, T + 5); minin(T + 6, T + 7);
        minin(T, T + 2); minin(T + 4, T + 6);
        minin(T, T + 4);
        if (!init[T] || pad[T]) ok = false;
        emit(3, o, T);
    }
};

constexpr Prog build() {
    Builder b{};
    // sorted columns g_c at 8c (c=0..7); merge frames:
    constexpr int M12 = 64, M34 = 80, M56 = 96;
    constexpr int C28 = 120, C42 = 152, T0 = 220, T1 = 232;

    // outputs 0..1, cols g0..g7 (out_i window = g_i..g_{i+6})
    for (int c = 1; c <= 6; ++c) b.load_col(8 * c, c);
    b.merge_to(M34, 8 * 3, 7, 8 * 4, 7);
    b.merge_to(M56, 8 * 5, 7, 8 * 6, 7);
    b.merge_to(C28, M34, 14, M56, 14);            // sorted(g3..g6)
    b.merge_to(M12, 8 * 1, 7, 8 * 2, 7);
    b.merge_to(C42, C28, 28, M12, 14);            // sorted42(g1..g6)

    b.load_col(8 * 0, 0);
    b.select_med49(T0, C42, 8 * 0, 0);            // out0: g0..g6
    b.load_col(8 * 7, 7);
    b.select_med49(T1, C42, 8 * 7, 1);            // out1: g1..g7

    // ---- backward prune + min/max degradation ----
    Prog p{};
    bool needed[NSLOT] = {};
    int kindr[MAXOPS] = {};
    bool keep[MAXOPS] = {};
    for (int t = b.n - 1; t >= 0; --t) {
        Op o = b.ops[t];
        if (o.kind == 3) { keep[t] = true; kindr[t] = 3; needed[o.b] = true; }
        else if (o.kind == 0) {
            bool na = needed[o.a], nb = needed[o.b];
            if (na && nb)      { keep[t] = true; kindr[t] = 0; }
            else if (na)       { keep[t] = true; kindr[t] = 4; needed[o.b] = true; }
            else if (nb)       { keep[t] = true; kindr[t] = 5; needed[o.a] = true; }
        } else if (o.kind == 1) {
            if (needed[o.a]) { keep[t] = true; kindr[t] = 1; needed[o.a] = false; needed[o.b] = true; }
        } else if (o.kind == 2) {
            if (needed[o.a]) { keep[t] = true; kindr[t] = 2; needed[o.a] = false; }
        } else if (o.kind == 4) {
            if (needed[o.a]) { keep[t] = true; kindr[t] = 4; needed[o.b] = true; }
        } else if (o.kind == 5) {
            if (needed[o.b]) { keep[t] = true; kindr[t] = 5; needed[o.a] = true; }
        }
    }
    p.n = 0;
    for (int t = 0; t < b.n; ++t)
        if (keep[t]) { p.ops[p.n] = b.ops[t]; p.ops[p.n].kind = kindr[t]; ++p.n; }
    p.ok = b.ok;

    // ---- liveness: last-use flags (post-op liveness) ----
    bool live[NSLOT] = {};
    bool lu_a[MAXOPS] = {};
    bool lu_b[MAXOPS] = {};
    for (int t = p.n - 1; t >= 0; --t) {
        Op o = p.ops[t];
        if (o.kind == 0 || o.kind == 4 || o.kind == 5) {
            lu_a[t] = !live[o.a]; lu_b[t] = !live[o.b];
        } else if (o.kind == 1 || o.kind == 3) {
            lu_b[t] = !live[o.b];
        }
        // kill defs
        if (o.kind == 0) { live[o.a] = false; live[o.b] = false; }
        else if (o.kind == 1 || o.kind == 2 || o.kind == 4) live[o.a] = false;
        else if (o.kind == 5) live[o.b] = false;
        // gen uses
        if (o.kind == 0 || o.kind == 4 || o.kind == 5) { live[o.a] = true; live[o.b] = true; }
        else if (o.kind == 1 || o.kind == 3) live[o.b] = true;
    }
    // In-place results must always be live afterwards (else prune failed).
    for (int t = 0; t < p.n; ++t) {
        Op o = p.ops[t];
        if (o.kind == 0 && (lu_a[t] || lu_b[t])) p.ok = false;
        if (o.kind == 4 && lu_a[t]) p.ok = false;
        if (o.kind == 5 && lu_b[t]) p.ok = false;
    }

    // ---- linear-scan regalloc with precolored columns + mov coalescing ----
    int phys[NSLOT] = {};
    bool bound[NSLOT] = {};
    bool claimed[NCOLREG] = {};
    int freelist[NSLOT] = {};
    bool drop[MAXOPS] = {};
    int nfree = 0, nphys = NCOLREG;
    for (int t = 0; t < p.n; ++t) {
        Op o = p.ops[t];
        if (o.kind == 0) {                       // in-place both
            if (!bound[o.a] || !bound[o.b]) p.ok = false;
            p.ops[t].a = phys[o.a]; p.ops[t].b = phys[o.b];
        } else if (o.kind == 4) {                // a in-place, b pure source
            if (!bound[o.a] || !bound[o.b]) p.ok = false;
            p.ops[t].a = phys[o.a]; p.ops[t].b = phys[o.b];
            if (lu_b[t]) { freelist[nfree++] = phys[o.b]; bound[o.b] = false; }
        } else if (o.kind == 5) {                // b in-place, a pure source
            if (!bound[o.a] || !bound[o.b]) p.ok = false;
            p.ops[t].a = phys[o.a]; p.ops[t].b = phys[o.b];
            if (lu_a[t]) { freelist[nfree++] = phys[o.a]; bound[o.a] = false; }
        } else if (o.kind == 1) {                // mov a <- b
            if (!bound[o.b]) p.ok = false;
            int pb = phys[o.b];
            if (lu_b[t]) {                       // source dies: pure rename
                if (bound[o.a]) { freelist[nfree++] = phys[o.a]; bound[o.a] = false; }
                phys[o.a] = pb; bound[o.a] = true; bound[o.b] = false;
                drop[t] = true;
            } else {                             // real copy
                p.ops[t].b = pb;
                if (bound[o.a]) { freelist[nfree++] = phys[o.a]; bound[o.a] = false; }
                int pa = (nfree > 0) ? freelist[--nfree] : nphys++;
                phys[o.a] = pa; bound[o.a] = true;
                p.ops[t].a = pa;
            }
        } else if (o.kind == 2) {                // load a <- cols[b]: precolored
            if (o.b < 0 || o.b >= NCOLREG || claimed[o.b]) p.ok = false;
            else claimed[o.b] = true;
            if (bound[o.a]) { freelist[nfree++] = phys[o.a]; bound[o.a] = false; }
            phys[o.a] = o.b; bound[o.a] = true;
            drop[t] = true;
        } else {                                 // store med[a] <- v[b]
            if (!bound[o.b]) p.ok = false;
            p.ops[t].b = phys[o.b];
            if (lu_b[t]) { freelist[nfree++] = phys[o.b]; bound[o.b] = false; }
        }
        if (nphys > NSLOT || nfree > NSLOT) p.ok = false;
    }
    p.nphys = nphys;

    // ---- compact: drop coalesced movs and precolored loads ----
    int m = 0;
    p.noload = true;
    for (int t = 0; t < p.n; ++t) {
        if (drop[t]) continue;
        if (p.ops[t].kind == 2) p.noload = false;
        p.ops[m++] = p.ops[t];
    }
    p.n = m;
    return p;
}

constexpr Prog PROG = build();
static_assert(PROG.ok && PROG.n > 0 && PROG.n < 2000, "program build failed");
static_assert(PROG.noload, "a load op survived precoloring");
static_assert(PROG.nphys >= NCOLREG && PROG.nphys <= 160, "regalloc blew up");
constexpr int NPHYS = PROG.nphys;

// Register file is SCALAR u32; bit_cast to h2 around each comparator is free.
template <int I>
__device__ __forceinline__ void step(unsigned* v, unsigned* med) {
    constexpr Op o = PROG.ops[I];
    if constexpr (o.kind == 0) {
        h2 a = __builtin_bit_cast(h2, v[o.a]);
        h2 b = __builtin_bit_cast(h2, v[o.b]);
        v[o.a] = __builtin_bit_cast(unsigned, h2min(a, b));
        v[o.b] = __builtin_bit_cast(unsigned, h2max(a, b));
    } else if constexpr (o.kind == 1) {
        v[o.a] = v[o.b];
    } else if constexpr (o.kind == 3) {
        med[o.a] = v[o.b];
    } else if constexpr (o.kind == 4) {
        h2 a = __builtin_bit_cast(h2, v[o.a]);
        h2 b = __builtin_bit_cast(h2, v[o.b]);
        v[o.a] = __builtin_bit_cast(unsigned, h2min(a, b));
    } else {
        h2 a = __builtin_bit_cast(h2, v[o.a]);
        h2 b = __builtin_bit_cast(h2, v[o.b]);
        v[o.b] = __builtin_bit_cast(unsigned, h2max(a, b));
    }
    // Phase fence: cap the pre-RA scheduler's reordering window so live
    // ranges stay near the constexpr regalloc's model (else RA spills the
    // file into AGPRs and every CE pays a 3x accvgpr shuttle).
    if constexpr ((I & 15) == 15) __builtin_amdgcn_sched_barrier(0);
}

template <size_t... Is>
__device__ __forceinline__ void run_all(unsigned* v, unsigned* med,
                                        std::index_sequence<Is...>) {
    (step<(int)Is>(v, med), ...);
}

// Each thread: 2 (horizontal) x 2 (vertical, packed f16 halves) output pixels.
__global__ __launch_bounds__(256, 4) void median7x7_kernel(
        const float* __restrict__ img, float* __restrict__ out) {
    const int bc = blockIdx.z;
    const int tx = threadIdx.x;                    // 0..63
    const int ty = threadIdx.y;                    // 0..3
    const int x0 = (blockIdx.x * 64 + tx) * 2;     // 0..510
    const int y  = (blockIdx.y * 4 + ty) * 2;      // 0..510

    const float* base = img + (size_t)bc * (IMG_H * IMG_W);
    const bool okA = (x0 >= 4);          // cur[0] valid (g = x0-3)
    const bool okB = (x0 >= 2);          // cur[1],cur[2] valid
    const bool okD = (x0 <= 508);        // cur[5],cur[6] valid
    const bool okE = (x0 <= 506);        // cur[7] valid (g = x0+4)
    const int xa = okA ? (x0 - 4) : 0;
    const int xb = okB ? (x0 - 2) : 0;
    const int xd = okD ? (x0 + 2) : 508;
    const int xe = okE ? (x0 + 4) : 506;

    // Network register file (scalar u32). Precolored slots: v[c*7+d] holds
    // packed (img[y-3+d][gc], img[y-2+d][gc]) as 2xf16, gc = x0-3+c, c=0..7.
    unsigned v[NPHYS];
    float prv[8];
#pragma unroll
    for (int r = 0; r < 8; ++r) {
        const int yy = y - 3 + r;
        float2 A, B, C, D, E;
        if ((unsigned)yy < IMG_H) {   // wave-uniform (blockDim.x == 64)
            const float* rp = base + (size_t)yy * IMG_W;
            A = *(const float2*)(rp + xa);
            B = *(const float2*)(rp + xb);
            C = *(const float2*)(rp + x0);
            D = *(const float2*)(rp + xd);
            E = *(const float2*)(rp + xe);
        } else {
            A = make_float2(0.f, 0.f); B = A; C = A; D = A; E = A;
        }
        float cur[8];
        cur[0] = okA ? A.y : 0.f;
        cur[1] = okB ? B.x : 0.f; cur[2] = okB ? B.y : 0.f;
        cur[3] = C.x; cur[4] = C.y;
        cur[5] = okD ? D.x : 0.f; cur[6] = okD ? D.y : 0.f;
        cur[7] = okE ? E.x : 0.f;
        if (r > 0) {
#pragma unroll
            for (int c = 0; c < 8; ++c)
                v[c * 7 + (r - 1)] = __builtin_bit_cast(
                    unsigned, (h2)__builtin_amdgcn_cvt_pkrtz(prv[c], cur[c]));
        }
#pragma unroll
        for (int c = 0; c < 8; ++c) prv[c] = cur[c];
    }
    // Fence between prologue and network: loads stay unpinned above; the
    // network below is phase-pinned every 16 ops.
    __builtin_amdgcn_sched_barrier(0);

    unsigned med[2];
    run_all(v, med, std::make_index_sequence<(size_t)PROG.n>{});

    const h2 m0 = __builtin_bit_cast(h2, med[0]);
    const h2 m1 = __builtin_bit_cast(h2, med[1]);
    float* op = out + (size_t)bc * (IMG_H * IMG_W) + (size_t)y * IMG_W + x0;
    *(float2*)op = make_float2((float)m0.x, (float)m1.x);
    *(float2*)(op + IMG_W) = make_float2((float)m0.y, (float)m1.y);
}

extern "C" void kernel_launch(void* const* d_in, const int* in_sizes, int n_in,
                              void* d_out, int out_size, void* d_ws, size_t ws_size,
                              hipStream_t stream) {
    const float* img = (const float*)d_in[0];
    float* out = (float*)d_out;
    dim3 grid(4, 64, 24);
    dim3 block(64, 4, 1);
    hipLaunchKernelGGL(median7x7_kernel, grid, block, 0, stream, img, out);
}

// Round 8
// 104.738 us; speedup vs baseline: 1.0070x; 1.0070x over previous
//
#include <hip/hip_runtime.h>
#include <utility>

#define IMG_H 512
#define IMG_W 512

typedef _Float16 h2 __attribute__((ext_vector_type(2)));

// ---------------------------------------------------------------------------
// Round 16: ASM-PINNED PACKED EXECUTOR.
// r5/r6/r7 produced bit-identical counters (VGPR 40, ~46us, VALU ~70%)
// across element-type, liveness, and schedule changes => deterministic
// codegen inflation upstream of all three. Hand-count of the 2-wide program:
// ~320 post-prune ops ~= 500 packed instr + 180 prologue ~= 700 needed vs
// 1600 observed => ~3x per network op. Surviving theory: llvm.minnum.v2f16
// does NOT select v_pk_min_f16 — it scalarizes (2x v_min_f16 + op_sel/pack
// fixups) — same IR for h2 and u32-bitcast versions, insensitive to
// everything we varied. Fix/test: inline asm per CE pinning exactly
// v_pk_min_f16 + v_pk_max_f16 (early-clobber on min). launch_bounds(256,3)
// (~170 reg budget) so ~110-value peak cannot pressure-spill and confound.
// Predict: VALU instr/thread 1600->~750, kernel 46->~22-26us, VGPR 40->80+.
// Unchanged => codegen family falsified, pivot to algorithmic op reduction.
// kinds: 0 ce(a,b)  1 mov v[a]=v[b]  2 load v[a]=cols[b]  3 store med[a]=v[b]
//        4 v[a]=min(v[a],v[b])       5 v[b]=max(v[a],v[b])
// ---------------------------------------------------------------------------
struct Op { int kind, a, b; };
constexpr int NSLOT = 352;
constexpr int MAXOPS = 4096;
constexpr int NCOLREG = 56;            // 8 columns x 7 rows, precolored 0..55
struct Prog { Op ops[MAXOPS]; int n; int nphys; bool ok; bool noload; };

constexpr int pow2ceil(int x) { int p = 1; while (p < x) p += p; return p; }

struct Builder {
    Op ops[MAXOPS] = {};
    int n = 0;
    bool pad[NSLOT] = {};
    bool init[NSLOT] = {};
    bool ok = true;

    constexpr void emit(int k, int a, int b) {
        if (n < MAXOPS) ops[n++] = Op{k, a, b}; else ok = false;
    }
    constexpr void load(int s, int c) { emit(2, s, c); pad[s] = false; init[s] = true; }
    constexpr void mov(int d, int s) {
        if (!init[s] || d == s) ok = false;
        emit(1, d, s); pad[d] = pad[s]; init[d] = true;
    }
    constexpr void mkpad(int s) { pad[s] = true; init[s] = true; }
    constexpr void ce_(int a, int b) {
        if (!init[a] || !init[b]) { ok = false; return; }
        if (pad[a] && pad[b]) return;
        if (!pad[a] && pad[b]) return;                      // min stays low: no-op
        if (pad[a] && !pad[b]) {                            // value falls to a
            emit(1, a, b); pad[a] = false; pad[b] = true; return;
        }
        emit(0, a, b);
    }
    constexpr void maxin(int a, int b) {  // v[b] = max(v[a], v[b])
        if (!init[a] || !init[b] || pad[a] || pad[b]) ok = false;
        emit(5, a, b);
    }
    constexpr void minin(int a, int b) {  // v[a] = min(v[a], v[b])
        if (!init[a] || !init[b] || pad[a] || pad[b]) ok = false;
        emit(4, a, b);
    }
    constexpr void sort_run(int base, int len) {
        for (int p = 1; p < len; p += p)
            for (int k = p; k > 0; k /= 2)
                for (int j = k % p; j + k < len; j += k + k)
                    for (int i = 0; i < k; ++i)
                        if (i + j + k < len)
                            if ((i + j) / (p + p) == (i + j + k) / (p + p))
                                ce_(base + i + j, base + i + j + k);
    }
    constexpr void merge_stage(int base, int P) {
        int nn = 2 * P, p = P;
        for (int k = p; k > 0; k /= 2)
            for (int j = k % p; j + k < nn; j += k + k)
                for (int i = 0; i < k; ++i) {
                    int a = i + j, b = i + j + k;
                    if (b < nn && a / (p + p) == b / (p + p)) ce_(base + a, base + b);
                }
    }
    constexpr void load_col(int base, int c) {  // packed col c, sorted
        for (int r = 0; r < 7; ++r) load(base + r, c * 7 + r);
        sort_run(base, 7);
    }
    constexpr void place(int dst, int src, int len, int P) {
        for (int i = 0; i < len; ++i) mov(dst + i, src + i);
        for (int i = len; i < P; ++i) mkpad(dst + i);
    }
    constexpr void merge_to(int dst, int s1, int l1, int s2, int l2) {
        int P = pow2ceil(l1 > l2 ? l1 : l2);
        place(dst, s1, l1, P);
        place(dst + P, s2, l2, P);
        merge_stage(dst, P);
    }
    // rank-24 of sorted-42 at A ∪ sorted-7 at B (min-of-max identity)
    constexpr void select_med49(int T, int A, int B, int o) {
        for (int t = 0; t < 7; ++t) {
            mov(T + t, A + 17 + t);
            maxin(B + 6 - t, T + t);
        }
        mov(T + 7, A + 24);
        minin(T, T + 1); minin(T + 2, T + 3);
        minin(T + 4, T + 5); minin(T + 6, T + 7);
        minin(T, T + 2); minin(T + 4, T + 6);
        minin(T, T + 4);
        if (!init[T] || pad[T]) ok = false;
        emit(3, o, T);
    }
};

constexpr Prog build() {
    Builder b{};
    // sorted columns g_c at 8c (c=0..7); merge frames:
    constexpr int M12 = 64, M34 = 80, M56 = 96;
    constexpr int C28 = 120, C42 = 152, T0 = 220, T1 = 232;

    // outputs 0..1, cols g0..g7 (out_i window = g_i..g_{i+6})
    for (int c = 1; c <= 6; ++c) b.load_col(8 * c, c);
    b.merge_to(M34, 8 * 3, 7, 8 * 4, 7);
    b.merge_to(M56, 8 * 5, 7, 8 * 6, 7);
    b.merge_to(C28, M34, 14, M56, 14);            // sorted(g3..g6)
    b.merge_to(M12, 8 * 1, 7, 8 * 2, 7);
    b.merge_to(C42, C28, 28, M12, 14);            // sorted42(g1..g6)

    b.load_col(8 * 0, 0);
    b.select_med49(T0, C42, 8 * 0, 0);            // out0: g0..g6
    b.load_col(8 * 7, 7);
    b.select_med49(T1, C42, 8 * 7, 1);            // out1: g1..g7

    // ---- backward prune + min/max degradation ----
    Prog p{};
    bool needed[NSLOT] = {};
    int kindr[MAXOPS] = {};
    bool keep[MAXOPS] = {};
    for (int t = b.n - 1; t >= 0; --t) {
        Op o = b.ops[t];
        if (o.kind == 3) { keep[t] = true; kindr[t] = 3; needed[o.b] = true; }
        else if (o.kind == 0) {
            bool na = needed[o.a], nb = needed[o.b];
            if (na && nb)      { keep[t] = true; kindr[t] = 0; }
            else if (na)       { keep[t] = true; kindr[t] = 4; needed[o.b] = true; }
            else if (nb)       { keep[t] = true; kindr[t] = 5; needed[o.a] = true; }
        } else if (o.kind == 1) {
            if (needed[o.a]) { keep[t] = true; kindr[t] = 1; needed[o.a] = false; needed[o.b] = true; }
        } else if (o.kind == 2) {
            if (needed[o.a]) { keep[t] = true; kindr[t] = 2; needed[o.a] = false; }
        } else if (o.kind == 4) {
            if (needed[o.a]) { keep[t] = true; kindr[t] = 4; needed[o.b] = true; }
        } else if (o.kind == 5) {
            if (needed[o.b]) { keep[t] = true; kindr[t] = 5; needed[o.a] = true; }
        }
    }
    p.n = 0;
    for (int t = 0; t < b.n; ++t)
        if (keep[t]) { p.ops[p.n] = b.ops[t]; p.ops[p.n].kind = kindr[t]; ++p.n; }
    p.ok = b.ok;

    // ---- liveness: last-use flags (post-op liveness) ----
    bool live[NSLOT] = {};
    bool lu_a[MAXOPS] = {};
    bool lu_b[MAXOPS] = {};
    for (int t = p.n - 1; t >= 0; --t) {
        Op o = p.ops[t];
        if (o.kind == 0 || o.kind == 4 || o.kind == 5) {
            lu_a[t] = !live[o.a]; lu_b[t] = !live[o.b];
        } else if (o.kind == 1 || o.kind == 3) {
            lu_b[t] = !live[o.b];
        }
        // kill defs
        if (o.kind == 0) { live[o.a] = false; live[o.b] = false; }
        else if (o.kind == 1 || o.kind == 2 || o.kind == 4) live[o.a] = false;
        else if (o.kind == 5) live[o.b] = false;
        // gen uses
        if (o.kind == 0 || o.kind == 4 || o.kind == 5) { live[o.a] = true; live[o.b] = true; }
        else if (o.kind == 1 || o.kind == 3) live[o.b] = true;
    }
    // In-place results must always be live afterwards (else prune failed).
    for (int t = 0; t < p.n; ++t) {
        Op o = p.ops[t];
        if (o.kind == 0 && (lu_a[t] || lu_b[t])) p.ok = false;
        if (o.kind == 4 && lu_a[t]) p.ok = false;
        if (o.kind == 5 && lu_b[t]) p.ok = false;
    }

    // ---- linear-scan regalloc with precolored columns + mov coalescing ----
    int phys[NSLOT] = {};
    bool bound[NSLOT] = {};
    bool claimed[NCOLREG] = {};
    int freelist[NSLOT] = {};
    bool drop[MAXOPS] = {};
    int nfree = 0, nphys = NCOLREG;
    for (int t = 0; t < p.n; ++t) {
        Op o = p.ops[t];
        if (o.kind == 0) {                       // in-place both
            if (!bound[o.a] || !bound[o.b]) p.ok = false;
            p.ops[t].a = phys[o.a]; p.ops[t].b = phys[o.b];
        } else if (o.kind == 4) {                // a in-place, b pure source
            if (!bound[o.a] || !bound[o.b]) p.ok = false;
            p.ops[t].a = phys[o.a]; p.ops[t].b = phys[o.b];
            if (lu_b[t]) { freelist[nfree++] = phys[o.b]; bound[o.b] = false; }
        } else if (o.kind == 5) {                // b in-place, a pure source
            if (!bound[o.a] || !bound[o.b]) p.ok = false;
            p.ops[t].a = phys[o.a]; p.ops[t].b = phys[o.b];
            if (lu_a[t]) { freelist[nfree++] = phys[o.a]; bound[o.a] = false; }
        } else if (o.kind == 1) {                // mov a <- b
            if (!bound[o.b]) p.ok = false;
            int pb = phys[o.b];
            if (lu_b[t]) {                       // source dies: pure rename
                if (bound[o.a]) { freelist[nfree++] = phys[o.a]; bound[o.a] = false; }
                phys[o.a] = pb; bound[o.a] = true; bound[o.b] = false;
                drop[t] = true;
            } else {                             // real copy
                p.ops[t].b = pb;
                if (bound[o.a]) { freelist[nfree++] = phys[o.a]; bound[o.a] = false; }
                int pa = (nfree > 0) ? freelist[--nfree] : nphys++;
                phys[o.a] = pa; bound[o.a] = true;
                p.ops[t].a = pa;
            }
        } else if (o.kind == 2) {                // load a <- cols[b]: precolored
            if (o.b < 0 || o.b >= NCOLREG || claimed[o.b]) p.ok = false;
            else claimed[o.b] = true;
            if (bound[o.a]) { freelist[nfree++] = phys[o.a]; bound[o.a] = false; }
            phys[o.a] = o.b; bound[o.a] = true;
            drop[t] = true;
        } else {                                 // store med[a] <- v[b]
            if (!bound[o.b]) p.ok = false;
            p.ops[t].b = phys[o.b];
            if (lu_b[t]) { freelist[nfree++] = phys[o.b]; bound[o.b] = false; }
        }
        if (nphys > NSLOT || nfree > NSLOT) p.ok = false;
    }
    p.nphys = nphys;

    // ---- compact: drop coalesced movs and precolored loads ----
    int m = 0;
    p.noload = true;
    for (int t = 0; t < p.n; ++t) {
        if (drop[t]) continue;
        if (p.ops[t].kind == 2) p.noload = false;
        p.ops[m++] = p.ops[t];
    }
    p.n = m;
    return p;
}

constexpr Prog PROG = build();
static_assert(PROG.ok && PROG.n > 0 && PROG.n < 2000, "program build failed");
static_assert(PROG.noload, "a load op survived precoloring");
static_assert(PROG.nphys >= NCOLREG && PROG.nphys <= 160, "regalloc blew up");
constexpr int NPHYS = PROG.nphys;

// ASM-pinned executor: exactly one v_pk_min_f16 / v_pk_max_f16 per min/max.
template <int I>
__device__ __forceinline__ void step(unsigned* v, unsigned* med) {
    constexpr Op o = PROG.ops[I];
    if constexpr (o.kind == 0) {
        unsigned a = v[o.a], b = v[o.b], lo, hi;
        asm("v_pk_min_f16 %0, %2, %3\n\tv_pk_max_f16 %1, %2, %3"
            : "=&v"(lo), "=v"(hi) : "v"(a), "v"(b));
        v[o.a] = lo; v[o.b] = hi;
    } else if constexpr (o.kind == 1) {
        v[o.a] = v[o.b];
    } else if constexpr (o.kind == 3) {
        med[o.a] = v[o.b];
    } else if constexpr (o.kind == 4) {
        unsigned r;
        asm("v_pk_min_f16 %0, %1, %2" : "=v"(r) : "v"(v[o.a]), "v"(v[o.b]));
        v[o.a] = r;
    } else {
        unsigned r;
        asm("v_pk_max_f16 %0, %1, %2" : "=v"(r) : "v"(v[o.a]), "v"(v[o.b]));
        v[o.b] = r;
    }
}

template <size_t... Is>
__device__ __forceinline__ void run_all(unsigned* v, unsigned* med,
                                        std::index_sequence<Is...>) {
    (step<(int)Is>(v, med), ...);
}

// Each thread: 2 (horizontal) x 2 (vertical, packed f16 halves) output pixels.
__global__ __launch_bounds__(256, 3) void median7x7_kernel(
        const float* __restrict__ img, float* __restrict__ out) {
    const int bc = blockIdx.z;
    const int tx = threadIdx.x;                    // 0..63
    const int ty = threadIdx.y;                    // 0..3
    const int x0 = (blockIdx.x * 64 + tx) * 2;     // 0..510
    const int y  = (blockIdx.y * 4 + ty) * 2;      // 0..510

    const float* base = img + (size_t)bc * (IMG_H * IMG_W);
    const bool okA = (x0 >= 4);          // cur[0] valid (g = x0-3)
    const bool okB = (x0 >= 2);          // cur[1],cur[2] valid
    const bool okD = (x0 <= 508);        // cur[5],cur[6] valid
    const bool okE = (x0 <= 506);        // cur[7] valid (g = x0+4)
    const int xa = okA ? (x0 - 4) : 0;
    const int xb = okB ? (x0 - 2) : 0;
    const int xd = okD ? (x0 + 2) : 508;
    const int xe = okE ? (x0 + 4) : 506;

    // Network register file (scalar u32). Precolored slots: v[c*7+d] holds
    // packed (img[y-3+d][gc], img[y-2+d][gc]) as 2xf16, gc = x0-3+c, c=0..7.
    unsigned v[NPHYS];
    float prv[8];
#pragma unroll
    for (int r = 0; r < 8; ++r) {
        const int yy = y - 3 + r;
        float2 A, B, C, D, E;
        if ((unsigned)yy < IMG_H) {   // wave-uniform (blockDim.x == 64)
            const float* rp = base + (size_t)yy * IMG_W;
            A = *(const float2*)(rp + xa);
            B = *(const float2*)(rp + xb);
            C = *(const float2*)(rp + x0);
            D = *(const float2*)(rp + xd);
            E = *(const float2*)(rp + xe);
        } else {
            A = make_float2(0.f, 0.f); B = A; C = A; D = A; E = A;
        }
        float cur[8];
        cur[0] = okA ? A.y : 0.f;
        cur[1] = okB ? B.x : 0.f; cur[2] = okB ? B.y : 0.f;
        cur[3] = C.x; cur[4] = C.y;
        cur[5] = okD ? D.x : 0.f; cur[6] = okD ? D.y : 0.f;
        cur[7] = okE ? E.x : 0.f;
        if (r > 0) {
#pragma unroll
            for (int c = 0; c < 8; ++c)
                v[c * 7 + (r - 1)] = __builtin_bit_cast(
                    unsigned, (h2)__builtin_amdgcn_cvt_pkrtz(prv[c], cur[c]));
        }
#pragma unroll
        for (int c = 0; c < 8; ++c) prv[c] = cur[c];
    }

    unsigned med[2];
    run_all(v, med, std::make_index_sequence<(size_t)PROG.n>{});

    const h2 m0 = __builtin_bit_cast(h2, med[0]);
    const h2 m1 = __builtin_bit_cast(h2, med[1]);
    float* op = out + (size_t)bc * (IMG_H * IMG_W) + (size_t)y * IMG_W + x0;
    *(float2*)op = make_float2((float)m0.x, (float)m1.x);
    *(float2*)(op + IMG_W) = make_float2((float)m0.y, (float)m1.y);
}

extern "C" void kernel_launch(void* const* d_in, const int* in_sizes, int n_in,
                              void* d_out, int out_size, void* d_ws, size_t ws_size,
                              hipStream_t stream) {
    const float* img = (const float*)d_in[0];
    float* out = (float*)d_out;
    dim3 grid(4, 64, 24);
    dim3 block(64, 4, 1);
    hipLaunchKernelGGL(median7x7_kernel, grid, block, 0, stream, img, out);
}